// Round 1
// baseline (405.398 us; speedup 1.0000x reference)
//
#include <hip/hip_runtime.h>
#include <math.h>

#define D_MODEL 2048
#define NEXP    64
#define NROWS   32768
#define BM      64      // rows per block
#define BK      16      // k-chunk
#define PAD     4       // LDS pad (multiple of 4 keeps 16B alignment for b128)
#define LDX     (BM + PAD)   // 68 floats leading dim

// block = 256 threads = 4 waves; thread tile 4 rows x 4 experts.
// 512 blocks -> 2 blocks/CU, 8 waves/CU. fp32 VALU-bound (~55us floor).
__global__ __launch_bounds__(256, 2) void router_kernel(
    const float* __restrict__ x,      // [NROWS, D_MODEL]
    const float* __restrict__ gw,     // [NEXP, D_MODEL]
    const float* __restrict__ bias,   // [NEXP]
    float* __restrict__ out)          // [NROWS*2 weights][NROWS*2 indices-as-float]
{
    __shared__ alignas(16) float xs[BK][LDX];   // xs[k][row_local]
    __shared__ alignas(16) float ws[BK][LDX];   // ws[k][expert]
    __shared__ float logits[BM][NEXP + 1];      // +1 pad -> conflict-free column scans

    const int t  = threadIdx.x;
    const int b  = blockIdx.x;
    const int r0 = b * BM;

    const int rg  = t & 15;          // row group (16 groups of 4 rows)
    const int eg  = t >> 4;          // expert group (16 groups of 4 experts)
    const int rg4 = rg * 4;
    const int eg4 = eg * 4;

    // staging mapping: thread -> (row-or-expert = t/4, k-quad = t%4)
    const int sr  = t >> 2;          // 0..63
    const int skq = t & 3;           // 0..3
    const float* xrow = x  + (size_t)(r0 + sr) * D_MODEL + skq * 4;
    const float* wrow = gw + (size_t)sr        * D_MODEL + skq * 4;

    float acc[4][4];
#pragma unroll
    for (int i = 0; i < 4; ++i)
#pragma unroll
        for (int j = 0; j < 4; ++j) acc[i][j] = 0.f;

    // software-pipelined staging: loads for chunk k0 issued one iteration early
    float4 xv = *(const float4*)(xrow);
    float4 wv = *(const float4*)(wrow);

    for (int k0 = 0; k0 < D_MODEL; k0 += BK) {
        __syncthreads();   // previous chunk's compute done before overwrite
        {
            const int kq4 = skq * 4;
            xs[kq4 + 0][sr] = xv.x; xs[kq4 + 1][sr] = xv.y;
            xs[kq4 + 2][sr] = xv.z; xs[kq4 + 3][sr] = xv.w;
            ws[kq4 + 0][sr] = wv.x; ws[kq4 + 1][sr] = wv.y;
            ws[kq4 + 2][sr] = wv.z; ws[kq4 + 3][sr] = wv.w;
        }
        __syncthreads();

        // issue next chunk's global loads; latency hides under FMA block
        if (k0 + BK < D_MODEL) {
            xv = *(const float4*)(xrow + k0 + BK);
            wv = *(const float4*)(wrow + k0 + BK);
        }

#pragma unroll
        for (int k = 0; k < BK; ++k) {
            const float4 xq = *(const float4*)&xs[k][rg4];
            const float4 wq = *(const float4*)&ws[k][eg4];
            acc[0][0] = fmaf(xq.x, wq.x, acc[0][0]);
            acc[0][1] = fmaf(xq.x, wq.y, acc[0][1]);
            acc[0][2] = fmaf(xq.x, wq.z, acc[0][2]);
            acc[0][3] = fmaf(xq.x, wq.w, acc[0][3]);
            acc[1][0] = fmaf(xq.y, wq.x, acc[1][0]);
            acc[1][1] = fmaf(xq.y, wq.y, acc[1][1]);
            acc[1][2] = fmaf(xq.y, wq.z, acc[1][2]);
            acc[1][3] = fmaf(xq.y, wq.w, acc[1][3]);
            acc[2][0] = fmaf(xq.z, wq.x, acc[2][0]);
            acc[2][1] = fmaf(xq.z, wq.y, acc[2][1]);
            acc[2][2] = fmaf(xq.z, wq.z, acc[2][2]);
            acc[2][3] = fmaf(xq.z, wq.w, acc[2][3]);
            acc[3][0] = fmaf(xq.w, wq.x, acc[3][0]);
            acc[3][1] = fmaf(xq.w, wq.y, acc[3][1]);
            acc[3][2] = fmaf(xq.w, wq.z, acc[3][2]);
            acc[3][3] = fmaf(xq.w, wq.w, acc[3][3]);
        }
    }

    __syncthreads();
#pragma unroll
    for (int i = 0; i < 4; ++i)
#pragma unroll
        for (int j = 0; j < 4; ++j)
            logits[rg4 + i][eg4 + j] = acc[i][j];
    __syncthreads();

    // epilogue: one thread per row (threads 0..63)
    if (t < BM) {
        const int row = r0 + t;
        float m1 = -INFINITY, m2 = -INFINITY;
        int   e1 = 0, e2 = 0;
        // pass 1: top-2 with stable (lowest-index-on-tie) semantics via strict >
        for (int e = 0; e < NEXP; ++e) {
            const float l = logits[t][e] + bias[e];
            if (l > m1) { m2 = m1; e2 = e1; m1 = l; e1 = e; }
            else if (l > m2) { m2 = l; e2 = e; }
        }
        // pass 2: full softmax denominator (max-subtracted), as reference does
        float z = 0.f;
        for (int e = 0; e < NEXP; ++e)
            z += expf(logits[t][e] + bias[e] - m1);
        // p1 = 1/z, p2 = exp(m2-m1)/z; w_i = p_i / (p1 + p2 + 1e-8)
        const float p2    = expf(m2 - m1);
        const float denom = (1.f + p2) + 1e-8f * z;
        out[row * 2 + 0] = 1.f / denom;
        out[row * 2 + 1] = p2 / denom;
        float* oidx = out + 2 * NROWS;          // second output chunk
        oidx[row * 2 + 0] = (float)e1;
        oidx[row * 2 + 1] = (float)e2;
    }
}

extern "C" void kernel_launch(void* const* d_in, const int* in_sizes, int n_in,
                              void* d_out, int out_size, void* d_ws, size_t ws_size,
                              hipStream_t stream) {
    const float* x    = (const float*)d_in[0];   // [32768, 2048]
    const float* gw   = (const float*)d_in[1];   // [64, 2048]
    const float* bias = (const float*)d_in[2];   // [64]
    float* out = (float*)d_out;                  // 131072 floats
    (void)in_sizes; (void)n_in; (void)out_size; (void)d_ws; (void)ws_size;

    dim3 grid(NROWS / BM);   // 512
    dim3 block(256);
    router_kernel<<<grid, block, 0, stream>>>(x, gw, bias, out);
}